// Round 6
// baseline (447.174 us; speedup 1.0000x reference)
//
#include <hip/hip_runtime.h>

#define NN 384
#define HH 768
#define CHUNK 256   // k-chunk (floats) staged per round
#define CROW 260    // padded LDS row: 65 quads (odd) -> 8 broadcast rows hit 8 distinct bank-quads
#define L2E 1.4426950408889634f
#define TWO_L2E 2.8853900817779268f
#define INV_SQRT_H 0.03608439182435161f
#define ATT_L2E (INV_SQRT_H * L2E)   // att -> log2 domain in one constant

__device__ __forceinline__ float exp2_hw(float x) { return __builtin_amdgcn_exp2f(x); }
__device__ __forceinline__ float rcp_hw(float x) { return __builtin_amdgcn_rcpf(x); }

// ---------------- workspace layout (floats) ----------------
#define WS_E(ws)      ((ws))
#define WS_ET(ws)     ((ws) + NN * NN)
#define WS_ROWP(ws)   ((ws) + 2 * NN * NN)            // [48][384] partial row sums of E
#define WS_COLP(ws)   ((ws) + 2 * NN * NN + 48 * NN)  // [48][384] partial col sums of E
#define WS_ROWRS(ws)  ((ws) + 2 * NN * NN + 96 * NN)  // [384] 1/rowSum
#define WS_COLRS(ws)  (WS_ROWRS(ws) + NN)
#define WS_HYPERT(ws) (WS_COLRS(ws) + NN)
#define WS_HYPOT(ws)  (WS_HYPERT(ws) + NN)
#define WS_HP(ws)     (WS_HYPOT(ws) + NN)             // [768] hyper prototype (atomic acc)
#define WS_HQ(ws)     (WS_HP(ws) + HH)                // [768] hypo prototype (atomic acc)

// ---------------- K1: one 8x8 tile of E = exp(att) + tile-partial row/col sums ------------
// R2's proven core (lane-per-output, 4 waves k-split, 4 independent trans chains) with the
// LDS slashed 50.4KB -> 17.7KB by staging k in three 256-float chunks. R5 measured k_att
// latency-bound (VALUBusy 40%, Occupancy 12.5% ~ 1 wave/SIMD): the fix is residency, not
// issue width. launch_bounds(256,6) -> VGPR<=85, 6 blocks/CU, 6 waves/SIMD; 2304-block
// grid keeps CUs fed. tanh(z)=1-2/(e^{2z}+1), y pre-scaled by 2*log2e; no softmax max
// needed (|att| <= 27.72, exp2 range fp32-safe).
__global__ __launch_bounds__(256, 6) void k_att(const float* __restrict__ X,
                                                const float* __restrict__ Y,
                                                float* __restrict__ ws) {
    __shared__ float smem[16 * CROW];   // 16,640 B staging
    __shared__ float part[4][64];
    float* E = WS_E(ws);
    float* ET = WS_ET(ws);
    float* rowP = WS_ROWP(ws);
    float* colP = WS_COLP(ws);

    const int tid = threadIdx.x;
    const int tt = blockIdx.x;
    const int it = tt / 48, jt = tt - it * 48;
    const int i0 = it * 8, j0 = jt * 8;

    if (tt == 0) {   // zero hp/hq for K3's atomicAdd (stream-ordered; ws arrives poisoned)
        float* pz = WS_HP(ws);
#pragma unroll
        for (int q = 0; q < 6; q++) pz[tid + q * 256] = 0.f;
    }

    const int wv = tid >> 6, ln = tid & 63;
    const int i = ln >> 3, j = ln & 7;
    float a0 = 0.f, a1 = 0.f, a2 = 0.f, a3 = 0.f;

#pragma unroll
    for (int ch = 0; ch < 3; ch++) {
        // stage 8 X rows + 8 Y rows x 256 k: 1024 float4, 4 per thread, coalesced
#pragma unroll
        for (int p = 0; p < 4; p++) {
            int e = tid + p * 256;          // 0..1023
            int row = e >> 6, col = e & 63;
            float4 v;
            if (row < 8) {
                v = *(const float4*)(X + (i0 + row) * HH + ch * CHUNK + col * 4);
            } else {
                v = *(const float4*)(Y + (j0 + row - 8) * HH + ch * CHUNK + col * 4);
                v.x *= TWO_L2E; v.y *= TWO_L2E; v.z *= TWO_L2E; v.w *= TWO_L2E;
            }
            *(float4*)(smem + row * CROW + col * 4) = v;
        }
        __syncthreads();

        const float4* xr = (const float4*)(smem + i * CROW) + wv * 16;
        const float4* yr = (const float4*)(smem + (8 + j) * CROW) + wv * 16;
#pragma unroll
        for (int m = 0; m < 16; m++) {
            float4 a = xr[m];
            float4 b = yr[m];
            a0 += rcp_hw(exp2_hw(a.x * b.x) + 1.f);
            a1 += rcp_hw(exp2_hw(a.y * b.y) + 1.f);
            a2 += rcp_hw(exp2_hw(a.z * b.z) + 1.f);
            a3 += rcp_hw(exp2_hw(a.w * b.w) + 1.f);
        }
        __syncthreads();   // next chunk restages
    }

    part[wv][ln] = (a0 + a1) + (a2 + a3);
    __syncthreads();
    if (tid < 64) {
        float s = part[0][tid] + part[1][tid] + part[2][tid] + part[3][tid];
        float ev = exp2_hw((768.f - 2.f * s) * ATT_L2E);   // E = exp(att)
        int ii = tid >> 3, jj = tid & 7;
        E[(i0 + ii) * NN + (j0 + jj)] = ev;
        ET[(j0 + jj) * NN + (i0 + ii)] = ev;
        float rs = ev;   // row partial (sum over jj within tile)
        rs += __shfl_xor(rs, 1, 64); rs += __shfl_xor(rs, 2, 64); rs += __shfl_xor(rs, 4, 64);
        if (jj == 0) rowP[jt * NN + i0 + ii] = rs;
        float cs = ev;   // col partial (sum over ii within tile)
        cs += __shfl_xor(cs, 8, 64); cs += __shfl_xor(cs, 16, 64); cs += __shfl_xor(cs, 32, 64);
        if (ii == 0) colP[it * NN + j0 + jj] = cs;
    }
}

// ---------------- K2: typicalness vectors; blocks 0..383 cols, 384..767 rows ----------------
// Fully coalesced: [48][384] partial arrays + one contiguous E/ET row. Blocks 0 and 384
// publish the reciprocal row/col sums for K3.
__global__ __launch_bounds__(256) void k_typ(float* __restrict__ ws) {
    __shared__ float red[4];
    const int b = blockIdx.x, tid = threadIdx.x;
    const float* E = WS_E(ws);
    const float* ET = WS_ET(ws);
    const bool isCol = b < NN;
    const int x = isCol ? b : b - NN;
    const float* P = isCol ? WS_ROWP(ws) : WS_COLP(ws);
    const float* M = isCol ? ET : E;

    float s1 = 0.f, s2 = 0.f;
#pragma unroll 8
    for (int k = 0; k < 48; k++) {
        s1 += P[k * NN + tid];
        if (tid < 128) s2 += P[k * NN + tid + 256];
    }
    float r1 = rcp_hw(s1);
    float acc = M[x * NN + tid] * r1;
    float r2 = 0.f;
    if (tid < 128) {
        r2 = rcp_hw(s2);
        acc += M[x * NN + tid + 256] * r2;
    }
    if (isCol ? (b == 0) : (b == NN)) {   // publish reciprocals once for K3
        float* RS = isCol ? WS_ROWRS(ws) : WS_COLRS(ws);
        RS[tid] = r1;
        if (tid < 128) RS[tid + 256] = r2;
    }
#pragma unroll
    for (int o = 32; o; o >>= 1) acc += __shfl_xor(acc, o, 64);
    if ((tid & 63) == 0) red[tid >> 6] = acc;
    __syncthreads();
    if (tid == 0) {
        float S = (red[0] + red[1]) + (red[2] + red[3]);
        (isCol ? WS_HYPERT(ws) : WS_HYPOT(ws))[x] = S * (1.f / NN);
    }
}

// ---------------- K3: w-vectors + prototypes, fused ----------------
// 96 blocks, 8 w-values each. Block computes w_j by block-reduction, then applies the
// rank-1 update proto[d] += w_j * V[j][d]; one atomicAdd per (thread, d-slot) into ws
// (48 contenders spread over 1536 addresses, relaxed — cheap, unlike R4's hot-line RMW).
__global__ __launch_bounds__(256) void k_wp(const float* __restrict__ X,
                                            const float* __restrict__ Y,
                                            float* __restrict__ ws) {
    __shared__ float red[4];
    const int bb = blockIdx.x, tid = threadIdx.x;
    const bool hyperSide = bb < 48;               // w_hyper -> hp (uses ET, rowRS, hypo_typ, Y)
    const int jbase = (hyperSide ? bb : bb - 48) * 8;
    const float* M  = hyperSide ? WS_ET(ws) : WS_E(ws);
    const float* RS = hyperSide ? WS_ROWRS(ws) : WS_COLRS(ws);
    const float* T  = hyperSide ? WS_HYPOT(ws) : WS_HYPERT(ws);
    const float* V  = hyperSide ? Y : X;
    float* proto    = hyperSide ? WS_HP(ws) : WS_HQ(ws);

    float p0 = 0.f, p1 = 0.f, p2 = 0.f;
#pragma unroll
    for (int q = 0; q < 8; q++) {
        const int jj = jbase + q;
        float acc = M[jj * NN + tid] * RS[tid] * T[tid];
        if (tid < 128) acc += M[jj * NN + tid + 256] * RS[tid + 256] * T[tid + 256];
#pragma unroll
        for (int o = 32; o; o >>= 1) acc += __shfl_xor(acc, o, 64);
        if ((tid & 63) == 0) red[tid >> 6] = acc;
        __syncthreads();
        const float wj = (red[0] + red[1]) + (red[2] + red[3]);
        p0 = fmaf(wj, V[jj * HH + tid], p0);
        p1 = fmaf(wj, V[jj * HH + tid + 256], p1);
        p2 = fmaf(wj, V[jj * HH + tid + 512], p2);
        __syncthreads();   // red[] reused next q
    }
    atomicAdd(proto + tid, p0);
    atomicAdd(proto + tid + 256, p1);
    atomicAdd(proto + tid + 512, p2);
}

// ---------------- K4: feats + classifier (1 block, plain stores to out) ----------------
__global__ __launch_bounds__(256) void k_cls(const float* __restrict__ W,
                                             const float* __restrict__ bias,
                                             const float* __restrict__ ws,
                                             float* __restrict__ out) {
    __shared__ float red[3][4];
    const int t = threadIdx.x;
    const float* hp = WS_HP((float*)ws);
    const float* hq = WS_HQ((float*)ws);
    float acc0 = 0.f, acc1 = 0.f, acc2 = 0.f;
    for (int d = t; d < 4 * HH; d += 256) {
        int seg = d / HH, r = d - seg * HH;
        float f = (seg == 0) ? hp[r] : (seg == 1) ? hq[r] : (seg == 2) ? (hp[r] - hq[r]) : (hp[r] * hq[r]);
        acc0 += W[d] * f;
        acc1 += W[3072 + d] * f;
        acc2 += W[6144 + d] * f;
    }
#pragma unroll
    for (int o = 32; o; o >>= 1) {
        acc0 += __shfl_xor(acc0, o, 64);
        acc1 += __shfl_xor(acc1, o, 64);
        acc2 += __shfl_xor(acc2, o, 64);
    }
    if ((t & 63) == 0) {
        red[0][t >> 6] = acc0;
        red[1][t >> 6] = acc1;
        red[2][t >> 6] = acc2;
    }
    __syncthreads();
    if (t < 3)
        out[t] = red[t][0] + red[t][1] + red[t][2] + red[t][3] + bias[t];
}

extern "C" void kernel_launch(void* const* d_in, const int* in_sizes, int n_in,
                              void* d_out, int out_size, void* d_ws, size_t ws_size,
                              hipStream_t stream) {
    const float* X = (const float*)d_in[0];   // hypo_embeddings [384,768] fp32
    const float* Y = (const float*)d_in[1];   // hyper_embeddings [384,768] fp32
    const float* W = (const float*)d_in[2];   // W_cls [3,3072] fp32
    const float* B = (const float*)d_in[3];   // b_cls [3] fp32
    float* out = (float*)d_out;
    float* ws = (float*)d_ws;

    k_att<<<2304, 256, 0, stream>>>(X, Y, ws);
    k_typ<<<768, 256, 0, stream>>>(ws);
    k_wp<<<96, 256, 0, stream>>>(X, Y, ws);
    k_cls<<<1, 256, 0, stream>>>(W, B, ws, out);
}

// Round 7
// 121.668 us; speedup vs baseline: 3.6754x; 3.6754x over previous
//
#include <hip/hip_runtime.h>

#define NN 384
#define HH 768
#define CHUNK 256   // k-chunk (floats) staged per round
#define CROW 260    // padded LDS row: 65 quads (odd) -> 8 broadcast rows hit 8 distinct bank-quads
#define L2E 1.4426950408889634f
#define TWO_L2E 2.8853900817779268f
#define INV_SQRT_H 0.03608439182435161f
#define ATT_L2E (INV_SQRT_H * L2E)   // att -> log2 domain in one constant

__device__ __forceinline__ float exp2_hw(float x) { return __builtin_amdgcn_exp2f(x); }
__device__ __forceinline__ float rcp_hw(float x) { return __builtin_amdgcn_rcpf(x); }

// ---------------- workspace layout (floats) ----------------
#define WS_E(ws)      ((ws))
#define WS_ET(ws)     ((ws) + NN * NN)
#define WS_ROWP(ws)   ((ws) + 2 * NN * NN)            // [48][384] partial row sums of E
#define WS_COLP(ws)   ((ws) + 2 * NN * NN + 48 * NN)  // [48][384] partial col sums of E
#define WS_ROWRS(ws)  ((ws) + 2 * NN * NN + 96 * NN)  // [384] 1/rowSum
#define WS_COLRS(ws)  (WS_ROWRS(ws) + NN)
#define WS_HYPERT(ws) (WS_COLRS(ws) + NN)
#define WS_HYPOT(ws)  (WS_HYPERT(ws) + NN)
#define WS_HP(ws)     (WS_HYPOT(ws) + NN)             // [768] hyper prototype (atomic acc)
#define WS_HQ(ws)     (WS_HP(ws) + HH)                // [768] hypo prototype (atomic acc)

// ---------------- K1: one 8x8 tile of E = exp(att) + tile-partial row/col sums ------------
// R2's proven core (lane-per-output, 4 waves k-split, 4 independent trans chains), LDS
// 17.7KB via three 256-float k-chunks. NO min-waves launch bound: R6's (256,6) cap made
// the allocator emit 40 VGPRs + ~1.4KB/thread scratch spill (1.3GB HBM traffic, 375us).
// Natural allocation is ~68 VGPRs -> ~7 blocks/CU (VGPR-limited), 9 by LDS -> 28 waves/CU,
// 7 waves/SIMD x 4 chains = 28 independent trans streams to cover exp2->rcp latency.
// tanh(z)=1-2/(e^{2z}+1), y pre-scaled by 2*log2e; no softmax max needed (|att| <= 27.72).
__global__ __launch_bounds__(256) void k_att(const float* __restrict__ X,
                                             const float* __restrict__ Y,
                                             float* __restrict__ ws) {
    __shared__ float smem[16 * CROW];   // 16,640 B staging
    __shared__ float part[4][64];
    float* E = WS_E(ws);
    float* ET = WS_ET(ws);
    float* rowP = WS_ROWP(ws);
    float* colP = WS_COLP(ws);

    const int tid = threadIdx.x;
    const int tt = blockIdx.x;
    const int it = tt / 48, jt = tt - it * 48;
    const int i0 = it * 8, j0 = jt * 8;

    if (tt == 0) {   // zero hp/hq for K3's atomicAdd (stream-ordered; ws arrives poisoned)
        float* pz = WS_HP(ws);
#pragma unroll
        for (int q = 0; q < 6; q++) pz[tid + q * 256] = 0.f;
    }

    const int wv = tid >> 6, ln = tid & 63;
    const int i = ln >> 3, j = ln & 7;
    float a0 = 0.f, a1 = 0.f, a2 = 0.f, a3 = 0.f;

#pragma unroll
    for (int ch = 0; ch < 3; ch++) {
        // stage 8 X rows + 8 Y rows x 256 k: 1024 float4, 4 per thread, coalesced
#pragma unroll
        for (int p = 0; p < 4; p++) {
            int e = tid + p * 256;          // 0..1023
            int row = e >> 6, col = e & 63;
            float4 v;
            if (row < 8) {
                v = *(const float4*)(X + (i0 + row) * HH + ch * CHUNK + col * 4);
            } else {
                v = *(const float4*)(Y + (j0 + row - 8) * HH + ch * CHUNK + col * 4);
                v.x *= TWO_L2E; v.y *= TWO_L2E; v.z *= TWO_L2E; v.w *= TWO_L2E;
            }
            *(float4*)(smem + row * CROW + col * 4) = v;
        }
        __syncthreads();

        const float4* xr = (const float4*)(smem + i * CROW) + wv * 16;
        const float4* yr = (const float4*)(smem + (8 + j) * CROW) + wv * 16;
#pragma unroll
        for (int m = 0; m < 16; m++) {
            float4 a = xr[m];
            float4 b = yr[m];
            a0 += rcp_hw(exp2_hw(a.x * b.x) + 1.f);
            a1 += rcp_hw(exp2_hw(a.y * b.y) + 1.f);
            a2 += rcp_hw(exp2_hw(a.z * b.z) + 1.f);
            a3 += rcp_hw(exp2_hw(a.w * b.w) + 1.f);
        }
        __syncthreads();   // next chunk restages
    }

    part[wv][ln] = (a0 + a1) + (a2 + a3);
    __syncthreads();
    if (tid < 64) {
        float s = part[0][tid] + part[1][tid] + part[2][tid] + part[3][tid];
        float ev = exp2_hw((768.f - 2.f * s) * ATT_L2E);   // E = exp(att)
        int ii = tid >> 3, jj = tid & 7;
        E[(i0 + ii) * NN + (j0 + jj)] = ev;
        ET[(j0 + jj) * NN + (i0 + ii)] = ev;
        float rs = ev;   // row partial (sum over jj within tile)
        rs += __shfl_xor(rs, 1, 64); rs += __shfl_xor(rs, 2, 64); rs += __shfl_xor(rs, 4, 64);
        if (jj == 0) rowP[jt * NN + i0 + ii] = rs;
        float cs = ev;   // col partial (sum over ii within tile)
        cs += __shfl_xor(cs, 8, 64); cs += __shfl_xor(cs, 16, 64); cs += __shfl_xor(cs, 32, 64);
        if (ii == 0) colP[it * NN + j0 + jj] = cs;
    }
}

// ---------------- K2: typicalness vectors; blocks 0..383 cols, 384..767 rows ----------------
// Fully coalesced: [48][384] partial arrays + one contiguous E/ET row. Blocks 0 and 384
// publish the reciprocal row/col sums for K3.
__global__ __launch_bounds__(256) void k_typ(float* __restrict__ ws) {
    __shared__ float red[4];
    const int b = blockIdx.x, tid = threadIdx.x;
    const float* E = WS_E(ws);
    const float* ET = WS_ET(ws);
    const bool isCol = b < NN;
    const int x = isCol ? b : b - NN;
    const float* P = isCol ? WS_ROWP(ws) : WS_COLP(ws);
    const float* M = isCol ? ET : E;

    float s1 = 0.f, s2 = 0.f;
#pragma unroll 8
    for (int k = 0; k < 48; k++) {
        s1 += P[k * NN + tid];
        if (tid < 128) s2 += P[k * NN + tid + 256];
    }
    float r1 = rcp_hw(s1);
    float acc = M[x * NN + tid] * r1;
    float r2 = 0.f;
    if (tid < 128) {
        r2 = rcp_hw(s2);
        acc += M[x * NN + tid + 256] * r2;
    }
    if (isCol ? (b == 0) : (b == NN)) {   // publish reciprocals once for K3
        float* RS = isCol ? WS_ROWRS(ws) : WS_COLRS(ws);
        RS[tid] = r1;
        if (tid < 128) RS[tid + 256] = r2;
    }
#pragma unroll
    for (int o = 32; o; o >>= 1) acc += __shfl_xor(acc, o, 64);
    if ((tid & 63) == 0) red[tid >> 6] = acc;
    __syncthreads();
    if (tid == 0) {
        float S = (red[0] + red[1]) + (red[2] + red[3]);
        (isCol ? WS_HYPERT(ws) : WS_HYPOT(ws))[x] = S * (1.f / NN);
    }
}

// ---------------- K3: w-vectors + prototypes, fused ----------------
// 96 blocks, 8 w-values each. Block computes w_j by block-reduction, then applies the
// rank-1 update proto[d] += w_j * V[j][d]; one atomicAdd per (thread, d-slot) into ws
// (48 contenders spread over 1536 addresses, relaxed — cheap, unlike R4's hot-line RMW).
__global__ __launch_bounds__(256) void k_wp(const float* __restrict__ X,
                                            const float* __restrict__ Y,
                                            float* __restrict__ ws) {
    __shared__ float red[4];
    const int bb = blockIdx.x, tid = threadIdx.x;
    const bool hyperSide = bb < 48;               // w_hyper -> hp (uses ET, rowRS, hypo_typ, Y)
    const int jbase = (hyperSide ? bb : bb - 48) * 8;
    const float* M  = hyperSide ? WS_ET(ws) : WS_E(ws);
    const float* RS = hyperSide ? WS_ROWRS(ws) : WS_COLRS(ws);
    const float* T  = hyperSide ? WS_HYPOT(ws) : WS_HYPERT(ws);
    const float* V  = hyperSide ? Y : X;
    float* proto    = hyperSide ? WS_HP(ws) : WS_HQ(ws);

    float p0 = 0.f, p1 = 0.f, p2 = 0.f;
#pragma unroll
    for (int q = 0; q < 8; q++) {
        const int jj = jbase + q;
        float acc = M[jj * NN + tid] * RS[tid] * T[tid];
        if (tid < 128) acc += M[jj * NN + tid + 256] * RS[tid + 256] * T[tid + 256];
#pragma unroll
        for (int o = 32; o; o >>= 1) acc += __shfl_xor(acc, o, 64);
        if ((tid & 63) == 0) red[tid >> 6] = acc;
        __syncthreads();
        const float wj = (red[0] + red[1]) + (red[2] + red[3]);
        p0 = fmaf(wj, V[jj * HH + tid], p0);
        p1 = fmaf(wj, V[jj * HH + tid + 256], p1);
        p2 = fmaf(wj, V[jj * HH + tid + 512], p2);
        __syncthreads();   // red[] reused next q
    }
    atomicAdd(proto + tid, p0);
    atomicAdd(proto + tid + 256, p1);
    atomicAdd(proto + tid + 512, p2);
}

// ---------------- K4: feats + classifier (1 block, plain stores to out) ----------------
__global__ __launch_bounds__(256) void k_cls(const float* __restrict__ W,
                                             const float* __restrict__ bias,
                                             const float* __restrict__ ws,
                                             float* __restrict__ out) {
    __shared__ float red[3][4];
    const int t = threadIdx.x;
    const float* hp = WS_HP((float*)ws);
    const float* hq = WS_HQ((float*)ws);
    float acc0 = 0.f, acc1 = 0.f, acc2 = 0.f;
    for (int d = t; d < 4 * HH; d += 256) {
        int seg = d / HH, r = d - seg * HH;
        float f = (seg == 0) ? hp[r] : (seg == 1) ? hq[r] : (seg == 2) ? (hp[r] - hq[r]) : (hp[r] * hq[r]);
        acc0 += W[d] * f;
        acc1 += W[3072 + d] * f;
        acc2 += W[6144 + d] * f;
    }
#pragma unroll
    for (int o = 32; o; o >>= 1) {
        acc0 += __shfl_xor(acc0, o, 64);
        acc1 += __shfl_xor(acc1, o, 64);
        acc2 += __shfl_xor(acc2, o, 64);
    }
    if ((t & 63) == 0) {
        red[0][t >> 6] = acc0;
        red[1][t >> 6] = acc1;
        red[2][t >> 6] = acc2;
    }
    __syncthreads();
    if (t < 3)
        out[t] = red[t][0] + red[t][1] + red[t][2] + red[t][3] + bias[t];
}

extern "C" void kernel_launch(void* const* d_in, const int* in_sizes, int n_in,
                              void* d_out, int out_size, void* d_ws, size_t ws_size,
                              hipStream_t stream) {
    const float* X = (const float*)d_in[0];   // hypo_embeddings [384,768] fp32
    const float* Y = (const float*)d_in[1];   // hyper_embeddings [384,768] fp32
    const float* W = (const float*)d_in[2];   // W_cls [3,3072] fp32
    const float* B = (const float*)d_in[3];   // b_cls [3] fp32
    float* out = (float*)d_out;
    float* ws = (float*)d_ws;

    k_att<<<2304, 256, 0, stream>>>(X, Y, ws);
    k_typ<<<768, 256, 0, stream>>>(ws);
    k_wp<<<96, 256, 0, stream>>>(X, Y, ws);
    k_cls<<<1, 256, 0, stream>>>(W, B, ws, out);
}

// Round 8
// 115.980 us; speedup vs baseline: 3.8556x; 1.0490x over previous
//
#include <hip/hip_runtime.h>

#define NN 384
#define HH 768
#define HP 772   // padded LDS row: 8 row bases spread across bank quads, 16B aligned
#define L2E 1.4426950408889634f
#define TWO_L2E 2.8853900817779268f
#define INV_SQRT_H 0.03608439182435161f
#define ATT_L2E (INV_SQRT_H * L2E)   // att -> log2 domain in one constant

__device__ __forceinline__ float exp2_hw(float x) { return __builtin_amdgcn_exp2f(x); }
__device__ __forceinline__ float rcp_hw(float x) { return __builtin_amdgcn_rcpf(x); }

// ---------------- workspace layout (floats) ----------------
#define WS_E(ws)      ((ws))
#define WS_ET(ws)     ((ws) + NN * NN)
#define WS_ROWP(ws)   ((ws) + 2 * NN * NN)            // [48][384] partial row sums of E
#define WS_COLP(ws)   ((ws) + 2 * NN * NN + 48 * NN)  // [48][384] partial col sums of E
#define WS_ROWRS(ws)  ((ws) + 2 * NN * NN + 96 * NN)  // [384] 1/rowSum
#define WS_COLRS(ws)  (WS_ROWRS(ws) + NN)
#define WS_HYPERT(ws) (WS_COLRS(ws) + NN)
#define WS_HYPOT(ws)  (WS_HYPERT(ws) + NN)
#define WS_HP(ws)     (WS_HYPOT(ws) + NN)             // [768] hyper prototype (atomic acc)
#define WS_HQ(ws)     (WS_HP(ws) + HH)                // [768] hypo prototype (atomic acc)

// ---------------- K1: one 8x8 tile of E = exp(att) + tile-partial row/col sums ------------
// EXACT R0/R2 core (the form measured ~17us via R4's arithmetic): single-stage 50.4KB LDS,
// 772-float padded rows, 6 float4/thread staging, 2 syncthreads total, 4 waves k-split,
// 4 independent rcp(exp2+1) chains per thread. R7's 3-chunk staging (6 syncs, smaller
// load bursts) regressed ~10us — reverted. tanh(z)=1-2/(e^{2z}+1), y pre-scaled by
// 2*log2e; no softmax max needed: |att| <= 27.72 so exp2(att*L2E) in [9e-13,1.1e12].
__global__ __launch_bounds__(256) void k_att(const float* __restrict__ X,
                                             const float* __restrict__ Y,
                                             float* __restrict__ ws) {
    __shared__ float smem[16 * HP + 256];
    float* xs = smem;
    float* ys = smem + 8 * HP;
    float* part = smem + 16 * HP;
    float* E = WS_E(ws);
    float* ET = WS_ET(ws);
    float* rowP = WS_ROWP(ws);
    float* colP = WS_COLP(ws);

    const int tid = threadIdx.x;
    const int tt = blockIdx.x;
    const int it = tt / 48, jt = tt - it * 48;
    const int i0 = it * 8, j0 = jt * 8;

    if (tt == 0) {   // zero hp/hq for K3's atomicAdd (stream-ordered; ws arrives poisoned)
        float* pz = WS_HP(ws);
#pragma unroll
        for (int q = 0; q < 6; q++) pz[tid + q * 256] = 0.f;
    }

    const float4* gx = (const float4*)(X + i0 * HH);
    const float4* gy = (const float4*)(Y + j0 * HH);
#pragma unroll
    for (int p = 0; p < 6; p++) {
        int e = tid + p * 256;
        int r = e / 192, c = e - r * 192;
        float4 vx = gx[e];
        float4 vy = gy[e];
        ((float4*)(xs + r * HP))[c] = vx;
        vy.x *= TWO_L2E; vy.y *= TWO_L2E; vy.z *= TWO_L2E; vy.w *= TWO_L2E;
        ((float4*)(ys + r * HP))[c] = vy;
    }
    __syncthreads();

    const int wv = tid >> 6, ln = tid & 63;
    const int i = ln >> 3, j = ln & 7;
    const float4* xr = (const float4*)(xs + i * HP) + wv * 48;
    const float4* yr = (const float4*)(ys + j * HP) + wv * 48;
    float a0 = 0.f, a1 = 0.f, a2 = 0.f, a3 = 0.f;
#pragma unroll 8
    for (int m = 0; m < 48; m++) {
        float4 a = xr[m];
        float4 b = yr[m];
        a0 += rcp_hw(exp2_hw(a.x * b.x) + 1.f);
        a1 += rcp_hw(exp2_hw(a.y * b.y) + 1.f);
        a2 += rcp_hw(exp2_hw(a.z * b.z) + 1.f);
        a3 += rcp_hw(exp2_hw(a.w * b.w) + 1.f);
    }
    part[wv * 64 + ln] = (a0 + a1) + (a2 + a3);
    __syncthreads();
    if (tid < 64) {
        float s = part[tid] + part[64 + tid] + part[128 + tid] + part[192 + tid];
        float ev = exp2_hw((768.f - 2.f * s) * ATT_L2E);   // E = exp(att)
        int ii = tid >> 3, jj = tid & 7;
        E[(i0 + ii) * NN + (j0 + jj)] = ev;
        ET[(j0 + jj) * NN + (i0 + ii)] = ev;
        float rs = ev;   // row partial (sum over jj within tile)
        rs += __shfl_xor(rs, 1, 64); rs += __shfl_xor(rs, 2, 64); rs += __shfl_xor(rs, 4, 64);
        if (jj == 0) rowP[jt * NN + i0 + ii] = rs;
        float cs = ev;   // col partial (sum over ii within tile)
        cs += __shfl_xor(cs, 8, 64); cs += __shfl_xor(cs, 16, 64); cs += __shfl_xor(cs, 32, 64);
        if (ii == 0) colP[it * NN + j0 + jj] = cs;
    }
}

// ---------------- K2: typicalness vectors; blocks 0..383 cols, 384..767 rows ----------------
// Fully coalesced: [48][384] partial arrays + one contiguous E/ET row. Blocks 0 and 384
// publish the reciprocal row/col sums for K3.
__global__ __launch_bounds__(256) void k_typ(float* __restrict__ ws) {
    __shared__ float red[4];
    const int b = blockIdx.x, tid = threadIdx.x;
    const float* E = WS_E(ws);
    const float* ET = WS_ET(ws);
    const bool isCol = b < NN;
    const int x = isCol ? b : b - NN;
    const float* P = isCol ? WS_ROWP(ws) : WS_COLP(ws);
    const float* M = isCol ? ET : E;

    float s1 = 0.f, s2 = 0.f;
#pragma unroll 8
    for (int k = 0; k < 48; k++) {
        s1 += P[k * NN + tid];
        if (tid < 128) s2 += P[k * NN + tid + 256];
    }
    float r1 = rcp_hw(s1);
    float acc = M[x * NN + tid] * r1;
    float r2 = 0.f;
    if (tid < 128) {
        r2 = rcp_hw(s2);
        acc += M[x * NN + tid + 256] * r2;
    }
    if (isCol ? (b == 0) : (b == NN)) {   // publish reciprocals once for K3
        float* RS = isCol ? WS_ROWRS(ws) : WS_COLRS(ws);
        RS[tid] = r1;
        if (tid < 128) RS[tid + 256] = r2;
    }
#pragma unroll
    for (int o = 32; o; o >>= 1) acc += __shfl_xor(acc, o, 64);
    if ((tid & 63) == 0) red[tid >> 6] = acc;
    __syncthreads();
    if (tid == 0) {
        float S = (red[0] + red[1]) + (red[2] + red[3]);
        (isCol ? WS_HYPERT(ws) : WS_HYPOT(ws))[x] = S * (1.f / NN);
    }
}

// ---------------- K3: w-vectors + prototypes, fused ----------------
// 96 blocks, 8 w-values each. Block computes w_j by block-reduction, then applies the
// rank-1 update proto[d] += w_j * V[j][d]; one atomicAdd per (thread, d-slot) into ws
// (48 contenders spread over 1536 addresses, relaxed — cheap, unlike R4's hot-line RMW).
__global__ __launch_bounds__(256) void k_wp(const float* __restrict__ X,
                                            const float* __restrict__ Y,
                                            float* __restrict__ ws) {
    __shared__ float red[4];
    const int bb = blockIdx.x, tid = threadIdx.x;
    const bool hyperSide = bb < 48;               // w_hyper -> hp (uses ET, rowRS, hypo_typ, Y)
    const int jbase = (hyperSide ? bb : bb - 48) * 8;
    const float* M  = hyperSide ? WS_ET(ws) : WS_E(ws);
    const float* RS = hyperSide ? WS_ROWRS(ws) : WS_COLRS(ws);
    const float* T  = hyperSide ? WS_HYPOT(ws) : WS_HYPERT(ws);
    const float* V  = hyperSide ? Y : X;
    float* proto    = hyperSide ? WS_HP(ws) : WS_HQ(ws);

    float p0 = 0.f, p1 = 0.f, p2 = 0.f;
#pragma unroll
    for (int q = 0; q < 8; q++) {
        const int jj = jbase + q;
        float acc = M[jj * NN + tid] * RS[tid] * T[tid];
        if (tid < 128) acc += M[jj * NN + tid + 256] * RS[tid + 256] * T[tid + 256];
#pragma unroll
        for (int o = 32; o; o >>= 1) acc += __shfl_xor(acc, o, 64);
        if ((tid & 63) == 0) red[tid >> 6] = acc;
        __syncthreads();
        const float wj = (red[0] + red[1]) + (red[2] + red[3]);
        p0 = fmaf(wj, V[jj * HH + tid], p0);
        p1 = fmaf(wj, V[jj * HH + tid + 256], p1);
        p2 = fmaf(wj, V[jj * HH + tid + 512], p2);
        __syncthreads();   // red[] reused next q
    }
    atomicAdd(proto + tid, p0);
    atomicAdd(proto + tid + 256, p1);
    atomicAdd(proto + tid + 512, p2);
}

// ---------------- K4: feats + classifier (1 block, plain stores to out) ----------------
__global__ __launch_bounds__(256) void k_cls(const float* __restrict__ W,
                                             const float* __restrict__ bias,
                                             const float* __restrict__ ws,
                                             float* __restrict__ out) {
    __shared__ float red[3][4];
    const int t = threadIdx.x;
    const float* hp = WS_HP((float*)ws);
    const float* hq = WS_HQ((float*)ws);
    float acc0 = 0.f, acc1 = 0.f, acc2 = 0.f;
    for (int d = t; d < 4 * HH; d += 256) {
        int seg = d / HH, r = d - seg * HH;
        float f = (seg == 0) ? hp[r] : (seg == 1) ? hq[r] : (seg == 2) ? (hp[r] - hq[r]) : (hp[r] * hq[r]);
        acc0 += W[d] * f;
        acc1 += W[3072 + d] * f;
        acc2 += W[6144 + d] * f;
    }
#pragma unroll
    for (int o = 32; o; o >>= 1) {
        acc0 += __shfl_xor(acc0, o, 64);
        acc1 += __shfl_xor(acc1, o, 64);
        acc2 += __shfl_xor(acc2, o, 64);
    }
    if ((t & 63) == 0) {
        red[0][t >> 6] = acc0;
        red[1][t >> 6] = acc1;
        red[2][t >> 6] = acc2;
    }
    __syncthreads();
    if (t < 3)
        out[t] = red[t][0] + red[t][1] + red[t][2] + red[t][3] + bias[t];
}

extern "C" void kernel_launch(void* const* d_in, const int* in_sizes, int n_in,
                              void* d_out, int out_size, void* d_ws, size_t ws_size,
                              hipStream_t stream) {
    const float* X = (const float*)d_in[0];   // hypo_embeddings [384,768] fp32
    const float* Y = (const float*)d_in[1];   // hyper_embeddings [384,768] fp32
    const float* W = (const float*)d_in[2];   // W_cls [3,3072] fp32
    const float* B = (const float*)d_in[3];   // b_cls [3] fp32
    float* out = (float*)d_out;
    float* ws = (float*)d_ws;

    k_att<<<2304, 256, 0, stream>>>(X, Y, ws);
    k_typ<<<768, 256, 0, stream>>>(ws);
    k_wp<<<96, 256, 0, stream>>>(X, Y, ws);
    k_cls<<<1, 256, 0, stream>>>(W, B, ws, out);
}